// Round 2
// baseline (101.171 us; speedup 1.0000x reference)
//
#include <hip/hip_runtime.h>

typedef float  float4_t __attribute__((ext_vector_type(4)));
typedef int    int4_t   __attribute__((ext_vector_type(4)));

// Fused elementwise streamer over 8-element work units:
//   units [0, nv8)         : new_vals[8] = keep ? vals/kr : 0
//   units [nv8, nv8+ni8)   : out[E + ...] = (float)idxs[...]  (pass-through as f32)
//
// Outputs are written with nontemporal stores so the 192 MB output stream does
// not evict the 256 MB of inputs from the Infinity Cache between graph replays.
__global__ void SpAdjDropEdge_48541720379660_kernel(
    const float* __restrict__ vals,
    const int*   __restrict__ idxs,
    const float* __restrict__ rand_u,
    const float* __restrict__ keep_rate_p,
    float*       __restrict__ out,
    int nv8, int ni8)
{
    const float kr = keep_rate_p[0];
    const int total  = nv8 + ni8;
    const int stride = gridDim.x * blockDim.x;

    for (int i = blockIdx.x * blockDim.x + threadIdx.x; i < total; i += stride) {
        if (i < nv8) {
            const float4_t* vp = reinterpret_cast<const float4_t*>(vals)   + (size_t)i * 2;
            const float4_t* rp = reinterpret_cast<const float4_t*>(rand_u) + (size_t)i * 2;
            // issue all 4 loads before any use -> 4 loads in flight
            float4_t v0 = vp[0];
            float4_t v1 = vp[1];
            float4_t r0 = rp[0];
            float4_t r1 = rp[1];
            float4_t o0, o1;
#pragma unroll
            for (int j = 0; j < 4; ++j) {
                bool k0 = (floorf(r0[j] + kr) != 0.0f);
                bool k1 = (floorf(r1[j] + kr) != 0.0f);
                o0[j] = k0 ? (v0[j] / kr) : 0.0f;
                o1[j] = k1 ? (v1[j] / kr) : 0.0f;
            }
            float4_t* op = reinterpret_cast<float4_t*>(out) + (size_t)i * 2;
            __builtin_nontemporal_store(o0, op);
            __builtin_nontemporal_store(o1, op + 1);
        } else {
            const int k = i - nv8;
            const int4_t* ip = reinterpret_cast<const int4_t*>(idxs) + (size_t)k * 2;
            int4_t a = ip[0];
            int4_t b = ip[1];
            float4_t o0, o1;
#pragma unroll
            for (int j = 0; j < 4; ++j) {
                o0[j] = (float)a[j];   // node ids < 2^24 -> exact in f32
                o1[j] = (float)b[j];
            }
            float4_t* op = reinterpret_cast<float4_t*>(out + (size_t)nv8 * 8) + (size_t)k * 2;
            __builtin_nontemporal_store(o0, op);
            __builtin_nontemporal_store(o1, op + 1);
        }
    }
}

extern "C" void kernel_launch(void* const* d_in, const int* in_sizes, int n_in,
                              void* d_out, int out_size, void* d_ws, size_t ws_size,
                              hipStream_t stream)
{
    const float* vals   = (const float*)d_in[0];
    const int*   idxs   = (const int*)  d_in[1];
    const float* rand_u = (const float*)d_in[2];
    const float* kr     = (const float*)d_in[3];
    float*       out    = (float*)d_out;

    const int E  = in_sizes[0];       // 16,000,000  (divisible by 8)
    const int NI = in_sizes[1];       // 32,000,000  (divisible by 8)
    const int nv8 = E  / 8;
    const int ni8 = NI / 8;

    const int block = 256;
    const int grid  = 4096;           // grid-stride; ~6 units/thread

    SpAdjDropEdge_48541720379660_kernel<<<grid, block, 0, stream>>>(
        vals, idxs, rand_u, kr, out, nv8, ni8);
}

// Round 3
// 82.026 us; speedup vs baseline: 1.2334x; 1.2334x over previous
//
#include <hip/hip_runtime.h>

typedef float  float4_t __attribute__((ext_vector_type(4)));
typedef int    int4_t   __attribute__((ext_vector_type(4)));

// Exact-cover elementwise streamer, one vec4 unit per thread:
//   units [0, nv4)        : new_vals = keep ? vals/kr : 0
//   units [nv4, nv4+ni4)  : out[E + j] = (float)idxs[j]  (pass-through as f32)
__global__ void SpAdjDropEdge_48541720379660_kernel(
    const float* __restrict__ vals,
    const int*   __restrict__ idxs,
    const float* __restrict__ rand_u,
    const float* __restrict__ keep_rate_p,
    float*       __restrict__ out,
    int nv4, int total)
{
    const int i = blockIdx.x * blockDim.x + threadIdx.x;
    if (i >= total) return;

    const float kr = keep_rate_p[0];

    if (i < nv4) {
        float4_t v = reinterpret_cast<const float4_t*>(vals)[i];
        float4_t r = reinterpret_cast<const float4_t*>(rand_u)[i];
        float4_t o;
#pragma unroll
        for (int j = 0; j < 4; ++j) {
            // reference: mask = floor(rand_u + keep_rate) != 0
            bool keep = (floorf(r[j] + kr) != 0.0f);
            o[j] = keep ? (v[j] / kr) : 0.0f;
        }
        reinterpret_cast<float4_t*>(out)[i] = o;
    } else {
        const int k = i - nv4;
        int4_t id = reinterpret_cast<const int4_t*>(idxs)[k];
        float4_t o;
#pragma unroll
        for (int j = 0; j < 4; ++j) {
            o[j] = (float)id[j];   // node ids < 2^24 -> exact in f32
        }
        reinterpret_cast<float4_t*>(out + (size_t)nv4 * 4)[k] = o;
    }
}

extern "C" void kernel_launch(void* const* d_in, const int* in_sizes, int n_in,
                              void* d_out, int out_size, void* d_ws, size_t ws_size,
                              hipStream_t stream)
{
    const float* vals   = (const float*)d_in[0];
    const int*   idxs   = (const int*)  d_in[1];
    const float* rand_u = (const float*)d_in[2];
    const float* kr     = (const float*)d_in[3];
    float*       out    = (float*)d_out;

    const int E  = in_sizes[0];       // 16,000,000  (divisible by 4)
    const int NI = in_sizes[1];       // 32,000,000  (divisible by 4)
    const int nv4   = E  / 4;
    const int ni4   = NI / 4;
    const int total = nv4 + ni4;      // 12,000,000 vec4 units

    const int block = 256;
    const int grid  = (total + block - 1) / block;   // exact cover: 1 unit/thread

    SpAdjDropEdge_48541720379660_kernel<<<grid, block, 0, stream>>>(
        vals, idxs, rand_u, kr, out, nv4, total);
}